// Round 6
// baseline (375.431 us; speedup 1.0000x reference)
//
#include <hip/hip_runtime.h>
#include <hip/hip_bf16.h>
#include <math.h>

// H2R detector: score map -> 3x3 NMS peaks -> per-batch top-1000 -> ROIs.
// [B=32,1,512,512] fp32 inputs; out = rois[32,1000,5] ++ scores[32,1000]
// ++ valid[32,1000] = 224000 floats.
//
// Scoring replicates numpy's SIMD (Cephes) fp32 expf op-for-op (verified
// bit-exact rounds 5-10: absmax 0.0). DO NOT alter score or emit paths.
//
// Round 17: SINGLE-DISPATCH pipeline. The 2-kernel chain paid ~12-17us of
// graph-replay boundary per dispatch plus select2's launch. Now one kernel:
//   - every block: strip score+NMS (unchanged math); per-WAVE private hot
//     segments (register-counter append, no atomics); publishes a done
//     record {v,~v,v^C1,v^C2} with agent-release atomics. Poison-proof:
//     no uniform/alternating fill pattern satisfies all three relations,
//     so no memset dispatch is needed.
//   - strip-31 block of each batch = selector: after its own strip, polls
//     its batch's 256 done records (acquire), then in-block: window-hist
//     sum -> T -> stream exact per-seg prefixes (no zero tails) ->
//     ballot-append to LDS cand -> FULL-SCAN exact rank (LDS broadcast,
//     no cursor atomics) -> verbatim emit. Deadlock-free: <=32 pollers,
//     >=512 blocks resident capacity.
//   - fallback (window < K; never taken): self-contained per-batch
//     recompute in the selector via global hist + fbbuf, same rank/emit.

#define B_   32
#define H_   512
#define W_   512
#define HW_  (H_ * W_)
#define K_   1000
#define ROWS_ 16            // interior rows per strip
#define THR_  512           // threads per block (8 waves)
#define NSTRIP_ 32          // H_/ROWS_
#define NBUK_ 4096          // score buckets = bits >> 18 (score < 1.0)
#define CAND_ 2048          // candidate LDS capacity (nc ~ 1000-1150)
#define HSEG_ 112           // per-wave hot capacity (mean ~51, ~8 sigma)
#define NSEGB_ (NSTRIP_ * 8)               // 256 wave-segs per batch
#define HOTBITS_ 0x3F000000u               // fp32 bits of 0.5f (bucket 4032)
#define WBASE_ (NBUK_ - 64)                // 4032: window base bucket
#define FBCAP_ 45056                       // fallback per-batch peak capacity

#define C1_ 0x13579BDFu
#define C2_ 0xECA86420u

#define HL_BYTES_  ((size_t)B_ * NSEGB_ * HSEG_ * 8)      // 7,340,032
#define GW_BYTES_  ((size_t)B_ * NSTRIP_ * 64 * 4)        // 262,144
#define DN_BYTES_  ((size_t)B_ * NSEGB_ * 16)             // 131,072
#define GF_BYTES_  ((size_t)B_ * NBUK_ * 4)               // 524,288

// ---- numpy SIMD (Cephes) fp32 exp replica — bit-exact, do not touch -------
__device__ __forceinline__ float np_expf(float x) {
#pragma clang fp contract(off)
    const float log2e = 1.44269504088896341f;
    float z = x * log2e;
    float m = rintf(z);
    float r = fmaf(m, -0.693359375f, x);
    r = fmaf(m, 2.12194440e-4f, r);
    float r2 = r * r;
    float p = fmaf(1.9875691500e-4f, r, 1.3981999507e-3f);
    p = fmaf(p, r, 8.3334519073e-3f);
    p = fmaf(p, r, 4.1665795894e-2f);
    p = fmaf(p, r, 1.6666665459e-1f);
    p = fmaf(p, r, 5.0000001201e-1f);
    p = fmaf(p, r2, r);
    p = p + 1.0f;
    int mi = (int)m;
    float sc = __int_as_float((127 + mi) << 23);
    return p * sc;
}

__device__ __forceinline__ float sigmoid_np(float x) {
#pragma clang fp contract(off)
    float e = np_expf(-x);
    float d = 1.0f + e;
    return 1.0f / d;
}

__device__ __forceinline__ float score_ref(float r, float u) {
#pragma clang fp contract(off)
    float s  = sigmoid_np(r);
    float s2 = s * s;
    float su = sigmoid_np(u);
    float t  = 0.35f * su;
    float m  = 1.0f - t;
    return s2 * m;
}

__device__ __forceinline__ float sigmoid_fast(float x) {  // box geometry only
    return 1.0f / (1.0f + __expf(-x));
}

__device__ __forceinline__ bool seg_done(const unsigned int* dw, int seg,
                                         unsigned int* cnt) {
    unsigned int w0 = __hip_atomic_load(dw + seg * 4 + 0, __ATOMIC_ACQUIRE,
                                        __HIP_MEMORY_SCOPE_AGENT);
    unsigned int w1 = __hip_atomic_load(dw + seg * 4 + 1, __ATOMIC_RELAXED,
                                        __HIP_MEMORY_SCOPE_AGENT);
    unsigned int w2 = __hip_atomic_load(dw + seg * 4 + 2, __ATOMIC_RELAXED,
                                        __HIP_MEMORY_SCOPE_AGENT);
    unsigned int w3 = __hip_atomic_load(dw + seg * 4 + 3, __ATOMIC_RELAXED,
                                        __HIP_MEMORY_SCOPE_AGENT);
    *cnt = w0;
    return (w1 == ~w0) && (w2 == (w0 ^ C1_)) && (w3 == (w0 ^ C2_));
}

// ---- Single fused kernel: strips + per-batch selector ---------------------
__global__ __launch_bounds__(THR_, 8) void h2r_kernel(
    const float* __restrict__ route, const float* __restrict__ unc,
    const float* __restrict__ scale,
    unsigned long long* __restrict__ hotlist,
    unsigned int* __restrict__ ghw,
    unsigned int* __restrict__ done_,
    unsigned int* __restrict__ ghfb,
    unsigned long long* __restrict__ fbbuf,
    const int* __restrict__ ih_p, const int* __restrict__ iw_p,
    float* __restrict__ out)
{
    __shared__ __align__(16) unsigned char smb[(ROWS_ + 2) * W_ * 4]; // 36.9KB
    __shared__ unsigned int whist[64];
    __shared__ unsigned int wsum[64];
    __shared__ int segc[NSEGB_];          // 1 KB
    __shared__ int sh_T, sh_nc, sh_fb, sh_n, sh_fn;

    float (*sm)[W_] = (float (*)[W_])smb;

    const int tid   = threadIdx.x;
    const int lane  = tid & 63;
    const int wid   = tid >> 6;                  // 0..7
    const int strip = blockIdx.x;                // 0..31
    const int b     = blockIdx.y;                // 0..31
    const int r0    = strip * ROWS_;
    if (tid < 64) whist[tid] = 0u;

    const float4* rb4 = (const float4*)(route + (size_t)b * HW_);
    const float4* ub4 = (const float4*)(unc   + (size_t)b * HW_);
    unsigned long long* hseg =
        hotlist + ((size_t)b * NSEGB_ + strip * 8 + wid) * HSEG_;

    // ---- Phase 1: stage 18 halo rows (branchless), score, peak test ----
    {
        float4 rv[5], uv[5];
        int lrow[5], c4[5]; bool ok[5];
        #pragma unroll
        for (int k = 0; k < 5; ++k) {
            int slot = tid + k * THR_;
            slot = slot < 2303 ? slot : 2303;
            int row = slot >> 7;
            int gy  = r0 - 1 + row;
            lrow[k] = row; c4[k] = slot & 127;
            ok[k]   = (gy >= 0 && gy < H_);
            int cy  = gy < 0 ? 0 : (gy >= H_ ? H_ - 1 : gy);
            rv[k] = rb4[cy * 128 + c4[k]];
            uv[k] = ub4[cy * 128 + c4[k]];
        }
        #pragma unroll
        for (int k = 0; k < 5; ++k) {
            float4 s;
            s.x = score_ref(rv[k].x, uv[k].x);
            s.y = score_ref(rv[k].y, uv[k].y);
            s.z = score_ref(rv[k].z, uv[k].z);
            s.w = score_ref(rv[k].w, uv[k].w);
            if (!ok[k]) { s.x = -INFINITY; s.y = -INFINITY;
                          s.z = -INFINITY; s.w = -INFINITY; }
            *(float4*)&sm[lrow[k]][c4[k] * 4] = s;
        }
    }
    __syncthreads();

    const unsigned long long lt = (1ull << lane) - 1ull;
    int wn = 0;                                  // wave-uniform hot count
    #pragma unroll
    for (int j = 0; j < 4; ++j) {
        int g  = tid + j * THR_;                 // 0..2047
        int ly = 1 + (g >> 7);                   // 1..16
        int x0 = (g & 127) * 4;
        int gy = r0 + (ly - 1);
        float4 q0 = *(const float4*)&sm[ly - 1][x0];
        float4 q1 = *(const float4*)&sm[ly    ][x0];
        float4 q2 = *(const float4*)&sm[ly + 1][x0];
        bool hasL = (x0 > 0), hasR = (x0 + 4 < W_);
        float l0 = hasL ? sm[ly - 1][x0 - 1] : -INFINITY;
        float l1 = hasL ? sm[ly    ][x0 - 1] : -INFINITY;
        float l2 = hasL ? sm[ly + 1][x0 - 1] : -INFINITY;
        float e0 = hasR ? sm[ly - 1][x0 + 4] : -INFINITY;
        float e1 = hasR ? sm[ly    ][x0 + 4] : -INFINITY;
        float e2 = hasR ? sm[ly + 1][x0 + 4] : -INFINITY;
        float f_m1 = fmaxf(l0, fmaxf(l1, l2));
        float f_0  = fmaxf(q0.x, fmaxf(q1.x, q2.x));
        float f_1  = fmaxf(q0.y, fmaxf(q1.y, q2.y));
        float f_2  = fmaxf(q0.z, fmaxf(q1.z, q2.z));
        float f_3  = fmaxf(q0.w, fmaxf(q1.w, q2.w));
        float f_4  = fmaxf(e0, fmaxf(e1, e2));
        float tb0  = fmaxf(q0.x, q2.x);
        float tb1  = fmaxf(q0.y, q2.y);
        float tb2  = fmaxf(q0.z, q2.z);
        float tb3  = fmaxf(q0.w, q2.w);
        float vv[4] = { q1.x, q1.y, q1.z, q1.w };
        float mm[4];
        mm[0] = fmaxf(fmaxf(f_m1, f_1), tb0);
        mm[1] = fmaxf(fmaxf(f_0,  f_2), tb1);
        mm[2] = fmaxf(fmaxf(f_1,  f_3), tb2);
        mm[3] = fmaxf(fmaxf(f_2,  f_4), tb3);
        #pragma unroll
        for (int i = 0; i < 4; ++i) {
            bool take = (vv[i] >= mm[i]);
            unsigned int bits = __float_as_uint(vv[i]);
            bool hot = take && (bits >= HOTBITS_);
            unsigned long long hmk = __ballot(hot);
            if (hot) {
                int hp = wn + __popcll(hmk & lt);
                if (hp < HSEG_) {
                    unsigned int idx = (unsigned int)(gy * W_ + x0 + i);
                    hseg[hp] = ((unsigned long long)bits << 32)
                               | (0xFFFFFFFFu - idx);
                    atomicAdd(&whist[(bits >> 18) - WBASE_], 1u);
                }
            }
            wn += __popcll(hmk);
        }
    }
    __syncthreads();                             // whist complete

    // window hist store (wave 0) then per-wave done publish.
    if (tid < 64)
        ghw[(size_t)(b * NSTRIP_ + strip) * 64 + tid] = whist[tid];
    {
        int stored = wn < HSEG_ ? wn : HSEG_;
        if (lane == 0) {
            unsigned int v = (unsigned int)stored;
            unsigned int* d = done_ + ((size_t)b * NSEGB_ + strip * 8 + wid) * 4;
            __hip_atomic_store(d + 1, ~v,     __ATOMIC_RELAXED, __HIP_MEMORY_SCOPE_AGENT);
            __hip_atomic_store(d + 2, v ^ C1_, __ATOMIC_RELAXED, __HIP_MEMORY_SCOPE_AGENT);
            __hip_atomic_store(d + 3, v ^ C2_, __ATOMIC_RELAXED, __HIP_MEMORY_SCOPE_AGENT);
            __hip_atomic_store(d + 0, v,      __ATOMIC_RELEASE, __HIP_MEMORY_SCOPE_AGENT);
        }
    }

    if (strip != NSTRIP_ - 1) return;            // non-selectors done

    // ================= SELECT PHASE (one block per batch) =================
    if (tid == 0) { sh_fb = 0; sh_T = 1; sh_nc = 0; sh_n = 0; sh_fn = 0; }
    if (tid < 64) wsum[tid] = 0u;

    // Poll the batch's 256 done records (wave 0).
    if (wid == 0) {
        const unsigned int* dw = done_ + (size_t)b * NSEGB_ * 4;
        unsigned int c0, c1, c2, c3;
        for (;;) {
            bool ok = seg_done(dw, lane,       &c0);
            ok &= seg_done(dw, lane + 64,  &c1);
            ok &= seg_done(dw, lane + 128, &c2);
            ok &= seg_done(dw, lane + 192, &c3);
            if (__all(ok)) break;
            __builtin_amdgcn_s_sleep(1);
        }
        segc[lane]       = (int)c0;
        segc[lane + 64]  = (int)c1;
        segc[lane + 128] = (int)c2;
        segc[lane + 192] = (int)c3;
    }
    __syncthreads();

    // Window hist sum (8 KB read, L2/L3-warm).
    {
        const unsigned int* gw = ghw + (size_t)b * NSTRIP_ * 64;
        for (int i = tid; i < NSTRIP_ * 64; i += THR_) {
            unsigned int v = gw[i];
            if (v) atomicAdd(&wsum[i & 63], v);
        }
    }
    __syncthreads();

    // T within window (wave 0), else fallback flag.
    if (wid == 0) {
        int cnt = (int)wsum[lane];
        int sum = cnt;
        #pragma unroll
        for (int off = 32; off > 0; off >>= 1)
            sum += __shfl_down(sum, off, 64);
        sum = __shfl(sum, 0, 64);
        if (sum < K_) {
            if (lane == 0) sh_fb = 1;
        } else {
            int suf = cnt;
            #pragma unroll
            for (int off = 1; off < 64; off <<= 1) {
                int o = __shfl_down(suf, off, 64);
                suf += (lane + off < 64) ? o : 0;
            }
            bool cond = suf >= K_;
            unsigned long long mask = __ballot(cond);
            int ls = 63 - __builtin_clzll(mask);
            int ncv = __shfl(suf, ls, 64);
            if (lane == 0) { sh_T = WBASE_ + ls; sh_nc = ncv; }
        }
    }
    __syncthreads();
    const int fb = sh_fb;
    unsigned long long* cand = (unsigned long long*)smb;  // sm overlay (16 KB)

    if (!fb) {
        // ---- Fast path: stream exact per-seg prefixes, append >= T ----
        const unsigned int T = (unsigned int)sh_T;
        for (int s = wid; s < NSEGB_; s += 8) {
            int c = segc[s];
            const unsigned long long* hs =
                hotlist + ((size_t)b * NSEGB_ + s) * HSEG_;
            for (int base = 0; base < c; base += 64) {
                int i = base + lane;
                bool act = (i < c);
                unsigned long long key = act ? hs[i] : 0ull;
                bool take = act && ((unsigned int)(key >> 50) >= T);
                unsigned long long mk = __ballot(take);
                if (mk) {
                    int ldr = __ffsll(mk) - 1;
                    int bp = 0;
                    if (lane == ldr) bp = atomicAdd(&sh_n, __popcll(mk));
                    bp = __shfl(bp, ldr, 64);
                    if (take) {
                        int p = bp + __popcll(mk & lt);
                        if (p < CAND_) cand[p] = key;
                    }
                }
            }
        }
    } else {
        // ==== Fallback (never taken on sane data): full recompute ====
        unsigned int* gh = ghfb + (size_t)b * NBUK_;
        unsigned long long* fbb = fbbuf + (size_t)b * FBCAP_;
        for (int i = tid; i < NBUK_; i += THR_) gh[i] = 0u;
        __syncthreads();

        for (int st = 0; st < NSTRIP_; ++st) {
            const int rr = st * ROWS_;
            __syncthreads();
            for (int slot0 = 0; slot0 < 2304; slot0 += THR_) {
                int slot = slot0 + tid;
                if (slot < 2304) {
                    int row = slot >> 7;
                    int gy  = rr - 1 + row;
                    int c4  = slot & 127;
                    bool okr = (gy >= 0 && gy < H_);
                    int cy  = gy < 0 ? 0 : (gy >= H_ ? H_ - 1 : gy);
                    float4 r4 = rb4[cy * 128 + c4];
                    float4 u4 = ub4[cy * 128 + c4];
                    float4 s;
                    s.x = score_ref(r4.x, u4.x);
                    s.y = score_ref(r4.y, u4.y);
                    s.z = score_ref(r4.z, u4.z);
                    s.w = score_ref(r4.w, u4.w);
                    if (!okr) { s.x = -INFINITY; s.y = -INFINITY;
                                s.z = -INFINITY; s.w = -INFINITY; }
                    *(float4*)&sm[row][c4 * 4] = s;
                }
            }
            __syncthreads();
            for (int g0 = 0; g0 < 2048; g0 += THR_) {
                int g  = g0 + tid;
                int ly = 1 + (g >> 7);
                int x0 = (g & 127) * 4;
                int gy = rr + (ly - 1);
                float4 q0 = *(const float4*)&sm[ly - 1][x0];
                float4 q1 = *(const float4*)&sm[ly    ][x0];
                float4 q2 = *(const float4*)&sm[ly + 1][x0];
                bool hasL = (x0 > 0), hasR = (x0 + 4 < W_);
                float l0 = hasL ? sm[ly - 1][x0 - 1] : -INFINITY;
                float l1 = hasL ? sm[ly    ][x0 - 1] : -INFINITY;
                float l2 = hasL ? sm[ly + 1][x0 - 1] : -INFINITY;
                float e0 = hasR ? sm[ly - 1][x0 + 4] : -INFINITY;
                float e1 = hasR ? sm[ly    ][x0 + 4] : -INFINITY;
                float e2 = hasR ? sm[ly + 1][x0 + 4] : -INFINITY;
                float f_m1 = fmaxf(l0, fmaxf(l1, l2));
                float f_0  = fmaxf(q0.x, fmaxf(q1.x, q2.x));
                float f_1  = fmaxf(q0.y, fmaxf(q1.y, q2.y));
                float f_2  = fmaxf(q0.z, fmaxf(q1.z, q2.z));
                float f_3  = fmaxf(q0.w, fmaxf(q1.w, q2.w));
                float f_4  = fmaxf(e0, fmaxf(e1, e2));
                float tb0  = fmaxf(q0.x, q2.x);
                float tb1  = fmaxf(q0.y, q2.y);
                float tb2  = fmaxf(q0.z, q2.z);
                float tb3  = fmaxf(q0.w, q2.w);
                float vv[4] = { q1.x, q1.y, q1.z, q1.w };
                float mm[4];
                mm[0] = fmaxf(fmaxf(f_m1, f_1), tb0);
                mm[1] = fmaxf(fmaxf(f_0,  f_2), tb1);
                mm[2] = fmaxf(fmaxf(f_1,  f_3), tb2);
                mm[3] = fmaxf(fmaxf(f_2,  f_4), tb3);
                #pragma unroll
                for (int i = 0; i < 4; ++i) {
                    if (vv[i] >= mm[i]) {
                        unsigned int bits = __float_as_uint(vv[i]);
                        unsigned int idx  = (unsigned int)(gy * W_ + x0 + i);
                        int p = atomicAdd(&sh_fn, 1);
                        if (p < FBCAP_) {
                            fbb[p] = ((unsigned long long)bits << 32)
                                     | (0xFFFFFFFFu - idx);
                            atomicAdd(&gh[bits >> 18], 1u);
                        }
                    }
                }
            }
        }
        __syncthreads();                        // sm dead; gh complete

        if (wid == 0) {
            int Tv = 1, ncv = 0, total = 0;
            for (int c = NBUK_ / 64 - 1; c >= 0; --c) {
                int cnt = (int)gh[c * 64 + lane];
                int sum = cnt;
                #pragma unroll
                for (int off = 32; off > 0; off >>= 1)
                    sum += __shfl_down(sum, off, 64);
                sum = __shfl(sum, 0, 64);
                if (total + sum < K_) { total += sum; continue; }
                int suf = cnt;
                #pragma unroll
                for (int off = 1; off < 64; off <<= 1) {
                    int o = __shfl_down(suf, off, 64);
                    suf += (lane + off < 64) ? o : 0;
                }
                bool cond = (total + suf) >= K_;
                unsigned long long mask = __ballot(cond);
                int ls = 63 - __builtin_clzll(mask);
                Tv = c * 64 + ls;
                ncv = total + __shfl(suf, ls, 64);
                break;
            }
            if (Tv < 1) Tv = 1;
            if (lane == 0) { sh_T = Tv; sh_nc = ncv; }
        }
        __syncthreads();
        const unsigned int T = (unsigned int)sh_T;
        int n = sh_fn; if (n > FBCAP_) n = FBCAP_;
        for (int i0 = 0; i0 < n; i0 += THR_) {
            int i = i0 + tid;
            bool act = (i < n);
            unsigned long long key = act ? fbb[i] : 0ull;
            bool take = act && ((unsigned int)(key >> 50) >= T);
            unsigned long long mk = __ballot(take);
            if (mk) {
                int ldr = __ffsll(mk) - 1;
                int bp = 0;
                if (lane == ldr) bp = atomicAdd(&sh_n, __popcll(mk));
                bp = __shfl(bp, ldr, 64);
                if (take) {
                    int p = bp + __popcll(mk & lt);
                    if (p < CAND_) cand[p] = key;
                }
            }
        }
    }
    __syncthreads();

    // ---- Exact descending rank via full scan (keys unique) + emit ----
    const float fih = (float)(*ih_p);
    const float fiw = (float)(*iw_p);
    float* rois   = out;                       // [B,K,5]
    float* scores = out + (size_t)B_ * K_ * 5; // [B,K]
    float* validf = out + (size_t)B_ * K_ * 6; // [B,K]

    int ncA = sh_n; if (ncA > CAND_) ncA = CAND_;
    for (int p = tid; p < ncA; p += THR_) {
        unsigned long long key = cand[p];
        int r = 0;
        for (int q = 0; q < ncA; ++q)
            r += (cand[q] > key) ? 1 : 0;
        if (r < K_) {
            int o = b * K_ + r;
            unsigned int bits = (unsigned int)(key >> 32);
            float v = __uint_as_float(bits);
            unsigned int idx = 0xFFFFFFFFu - (unsigned int)(key & 0xFFFFFFFFull);
            int y = (int)(idx >> 9), x = (int)(idx & 511u);
            float cx = ((float)x + 0.5f) * 4.0f;
            float cy = ((float)y + 0.5f) * 4.0f;
            float ss = sigmoid_fast(scale[(size_t)b * HW_ + idx]);
            float su = sigmoid_fast(unc  [(size_t)b * HW_ + idx]);
            float side = (32.0f + ss * 480.0f) * (1.0f + 0.25f * su);
            float half = 0.5f * side;
            float x1 = fminf(fmaxf(cx - half, 0.0f), fiw - 1.0f);
            float y1 = fminf(fmaxf(cy - half, 0.0f), fih - 1.0f);
            float x2 = fminf(fmaxf(cx + half, 1.0f), fiw);
            float y2 = fminf(fmaxf(cy + half, 1.0f), fih);
            rois[o * 5 + 0] = (float)b;
            rois[o * 5 + 1] = x1; rois[o * 5 + 2] = y1;
            rois[o * 5 + 3] = x2; rois[o * 5 + 4] = y2;
            scores[o] = v; validf[o] = 1.0f;
        }
    }
    // Tail fill (only if fewer than K candidates exist — normally empty).
    for (int k = sh_nc + tid; k < K_; k += THR_) {
        int o = b * K_ + k;
        rois[o * 5 + 0] = 0.0f; rois[o * 5 + 1] = 0.0f;
        rois[o * 5 + 2] = 0.0f; rois[o * 5 + 3] = 0.0f;
        rois[o * 5 + 4] = 0.0f;
        scores[o] = 0.0f; validf[o] = 0.0f;
    }
}

extern "C" void kernel_launch(void* const* d_in, const int* in_sizes, int n_in,
                              void* d_out, int out_size, void* d_ws, size_t ws_size,
                              hipStream_t stream) {
    const float* route = (const float*)d_in[0];
    const float* scale = (const float*)d_in[1];
    const float* unc   = (const float*)d_in[2];
    const int*   ih    = (const int*)d_in[3];
    const int*   iw    = (const int*)d_in[4];
    float* out = (float*)d_out;

    // ws layout (no memset needed — done records are poison-proof):
    //   hotlist  7,340,032 B (32 x 256 x 112 x u64) — per-wave hot segments
    //   ghw        262,144 B (32 x 32 x 64 x u32)   — window hists
    //   done       131,072 B (32 x 256 x uint4)     — completion records
    //   ghfb       524,288 B (32 x 4096 x u32)      — fallback hist
    //   fbbuf   11,534,336 B (32 x 45056 x u64)     — fallback peaks
    unsigned char* base = (unsigned char*)d_ws;
    unsigned long long* hotlist = (unsigned long long*)base;
    unsigned int* ghw  = (unsigned int*)(base + HL_BYTES_);
    unsigned int* done_ = (unsigned int*)(base + HL_BYTES_ + GW_BYTES_);
    unsigned int* ghfb = (unsigned int*)(base + HL_BYTES_ + GW_BYTES_ + DN_BYTES_);
    unsigned long long* fbbuf =
        (unsigned long long*)(base + HL_BYTES_ + GW_BYTES_ + DN_BYTES_ + GF_BYTES_);

    dim3 g(NSTRIP_, B_);      // 32 strips x 32 batches, selector = strip 31
    h2r_kernel<<<g, THR_, 0, stream>>>(route, unc, scale, hotlist, ghw,
                                       done_, ghfb, fbbuf, ih, iw, out);
}

// Round 7
// 163.403 us; speedup vs baseline: 2.2976x; 2.2976x over previous
//
#include <hip/hip_runtime.h>
#include <hip/hip_bf16.h>
#include <math.h>

// H2R detector: score map -> 3x3 NMS peaks -> per-batch top-1000 -> ROIs.
// [B=32,1,512,512] fp32 inputs; out = rois[32,1000,5] ++ scores[32,1000]
// ++ valid[32,1000] = 224000 floats.
//
// Scoring replicates numpy's SIMD (Cephes) fp32 expf op-for-op (verified
// bit-exact rounds 5-10: absmax 0.0). DO NOT alter score or emit paths.
//
// Round 18: REVERT to the round-15 2-dispatch structure (best measured:
// 158.6us). Round 17's single-dispatch intra-grid polling (agent-scope
// acquire loads) throttled the whole memory fabric to 170 GB/s -> 2x
// regression. Lesson: no device-scope spin-polling on this chip.
// Deltas vs round 15 (both low-risk byte cuts):
//   - fused_peak stores the EXACT per-strip hot count (plain store) and no
//     longer zero-fills the hot-list tail (-~3 MB writes).
//   - select2 streams only the real per-strip prefixes (~120 KB/batch vs
//     224 KB). Same keys, same T rule, same cursor-scatter + segment rank
//     (order-independent, bit-identical output).

#define B_   32
#define H_   512
#define W_   512
#define HW_  (H_ * W_)
#define K_   1000
#define ROWS_ 16            // interior rows per strip
#define THR_  512           // threads per fused block (8 waves)
#define NSTRIP_ 32          // H_/ROWS_
#define NBUK_ 4096          // score buckets = bits >> 18 (score < 1.0)
#define GCAP_ 2048          // grouped-candidate LDS capacity (nc ~ 1000-1150)
#define HOTCAP_ 896         // per-strip hot-list capacity (mean ~420-560)
#define HOTBITS_ 0x3F000000u               // fp32 bits of 0.5f (bucket 4032)
#define WBASE_ (NBUK_ - 64)                // 4032: window base bucket
#define FBCAP_ 45056                       // fallback per-batch peak capacity

#define HL_BYTES_  ((size_t)B_ * NSTRIP_ * HOTCAP_ * 8)   // 7,340,032
#define GW_BYTES_  ((size_t)B_ * NSTRIP_ * 64 * 4)        // 262,144
#define HC_BYTES_  ((size_t)B_ * NSTRIP_ * 4)             // 4,096

// ---- numpy SIMD (Cephes) fp32 exp replica — bit-exact, do not touch -------
__device__ __forceinline__ float np_expf(float x) {
#pragma clang fp contract(off)
    const float log2e = 1.44269504088896341f;
    float z = x * log2e;
    float m = rintf(z);
    float r = fmaf(m, -0.693359375f, x);
    r = fmaf(m, 2.12194440e-4f, r);
    float r2 = r * r;
    float p = fmaf(1.9875691500e-4f, r, 1.3981999507e-3f);
    p = fmaf(p, r, 8.3334519073e-3f);
    p = fmaf(p, r, 4.1665795894e-2f);
    p = fmaf(p, r, 1.6666665459e-1f);
    p = fmaf(p, r, 5.0000001201e-1f);
    p = fmaf(p, r2, r);
    p = p + 1.0f;
    int mi = (int)m;
    float sc = __int_as_float((127 + mi) << 23);
    return p * sc;
}

__device__ __forceinline__ float sigmoid_np(float x) {
#pragma clang fp contract(off)
    float e = np_expf(-x);
    float d = 1.0f + e;
    return 1.0f / d;
}

__device__ __forceinline__ float score_ref(float r, float u) {
#pragma clang fp contract(off)
    float s  = sigmoid_np(r);
    float s2 = s * s;
    float su = sigmoid_np(u);
    float t  = 0.35f * su;
    float m  = 1.0f - t;
    return s2 * m;
}

__device__ __forceinline__ float sigmoid_fast(float x) {  // box geometry only
    return 1.0f / (1.0f + __expf(-x));
}

// ---- Fused: score strip + 3x3 peak test -> hot list + window hist ---------
__global__ __launch_bounds__(THR_, 4) void fused_peak_kernel(
    const float* __restrict__ route, const float* __restrict__ unc,
    unsigned long long* __restrict__ hotlist,
    unsigned int* __restrict__ ghw,
    int* __restrict__ hcnts)
{
    __shared__ float sm[ROWS_ + 2][W_];          // 18x512 = 36.9 KB
    __shared__ unsigned int whist[64];
    __shared__ int hcnt;

    const int tid   = threadIdx.x;
    const int lane  = tid & 63;
    const int strip = blockIdx.x;                // 0..31
    const int b     = blockIdx.y;                // 0..31
    const int r0    = strip * ROWS_;
    if (tid < 64) whist[tid] = 0u;
    if (tid == 0) hcnt = 0;

    const float4* rb4 = (const float4*)(route + (size_t)b * HW_);
    const float4* ub4 = (const float4*)(unc   + (size_t)b * HW_);
    unsigned long long* hseg =
        hotlist + (size_t)(b * NSTRIP_ + strip) * HOTCAP_;

    // Stage 18 halo rows: branchless (slot clamp), 10 loads in flight.
    float4 rv[5], uv[5];
    int lrow[5], c4[5]; bool ok[5];
    #pragma unroll
    for (int k = 0; k < 5; ++k) {
        int slot = tid + k * THR_;
        slot = slot < 2303 ? slot : 2303;
        int row = slot >> 7;
        int gy  = r0 - 1 + row;
        lrow[k] = row; c4[k] = slot & 127;
        ok[k]   = (gy >= 0 && gy < H_);
        int cy  = gy < 0 ? 0 : (gy >= H_ ? H_ - 1 : gy);
        rv[k] = rb4[cy * 128 + c4[k]];
        uv[k] = ub4[cy * 128 + c4[k]];
    }
    #pragma unroll
    for (int k = 0; k < 5; ++k) {
        float4 s;
        s.x = score_ref(rv[k].x, uv[k].x);
        s.y = score_ref(rv[k].y, uv[k].y);
        s.z = score_ref(rv[k].z, uv[k].z);
        s.w = score_ref(rv[k].w, uv[k].w);
        if (!ok[k]) { s.x = -INFINITY; s.y = -INFINITY;
                      s.z = -INFINITY; s.w = -INFINITY; }
        *(float4*)&sm[lrow[k]][c4[k] * 4] = s;
    }
    __syncthreads();

    // Peak test: 16x512 interior, 4-px groups, float4 reads + column max.
    // Only hot peaks (bits >= 0.5f) are emitted: ballot-aggregated append.
    const unsigned long long lt = (1ull << lane) - 1ull;
    #pragma unroll
    for (int j = 0; j < 4; ++j) {
        int g  = tid + j * THR_;                 // 0..2047
        int ly = 1 + (g >> 7);                   // 1..16
        int x0 = (g & 127) * 4;
        int gy = r0 + (ly - 1);
        float4 q0 = *(const float4*)&sm[ly - 1][x0];
        float4 q1 = *(const float4*)&sm[ly    ][x0];
        float4 q2 = *(const float4*)&sm[ly + 1][x0];
        bool hasL = (x0 > 0), hasR = (x0 + 4 < W_);
        float l0 = hasL ? sm[ly - 1][x0 - 1] : -INFINITY;
        float l1 = hasL ? sm[ly    ][x0 - 1] : -INFINITY;
        float l2 = hasL ? sm[ly + 1][x0 - 1] : -INFINITY;
        float e0 = hasR ? sm[ly - 1][x0 + 4] : -INFINITY;
        float e1 = hasR ? sm[ly    ][x0 + 4] : -INFINITY;
        float e2 = hasR ? sm[ly + 1][x0 + 4] : -INFINITY;
        float f_m1 = fmaxf(l0, fmaxf(l1, l2));
        float f_0  = fmaxf(q0.x, fmaxf(q1.x, q2.x));
        float f_1  = fmaxf(q0.y, fmaxf(q1.y, q2.y));
        float f_2  = fmaxf(q0.z, fmaxf(q1.z, q2.z));
        float f_3  = fmaxf(q0.w, fmaxf(q1.w, q2.w));
        float f_4  = fmaxf(e0, fmaxf(e1, e2));
        float tb0  = fmaxf(q0.x, q2.x);
        float tb1  = fmaxf(q0.y, q2.y);
        float tb2  = fmaxf(q0.z, q2.z);
        float tb3  = fmaxf(q0.w, q2.w);
        float vv[4] = { q1.x, q1.y, q1.z, q1.w };
        float mm[4];
        mm[0] = fmaxf(fmaxf(f_m1, f_1), tb0);
        mm[1] = fmaxf(fmaxf(f_0,  f_2), tb1);
        mm[2] = fmaxf(fmaxf(f_1,  f_3), tb2);
        mm[3] = fmaxf(fmaxf(f_2,  f_4), tb3);
        #pragma unroll
        for (int i = 0; i < 4; ++i) {
            bool take = (vv[i] >= mm[i]);
            unsigned int bits = __float_as_uint(vv[i]);
            bool hot = take && (bits >= HOTBITS_);
            unsigned long long hmk = __ballot(hot);
            if (hmk) {
                int ldr = __ffsll(hmk) - 1;
                int hb = 0;
                if (lane == ldr) hb = atomicAdd(&hcnt, __popcll(hmk));
                hb = __shfl(hb, ldr, 64);
                if (hot) {
                    int hp = hb + __popcll(hmk & lt);
                    if (hp < HOTCAP_) {
                        unsigned int idx = (unsigned int)(gy * W_ + x0 + i);
                        hseg[hp] = ((unsigned long long)bits << 32)
                                   | (0xFFFFFFFFu - idx);
                        atomicAdd(&whist[(bits >> 18) - WBASE_], 1u);
                    }
                }
            }
        }
    }
    __syncthreads();                             // whist + hcnt complete

    // Exact count (plain store) + window hist store. No zero-fill tails.
    if (tid == 0)
        hcnts[b * NSTRIP_ + strip] = hcnt < HOTCAP_ ? hcnt : HOTCAP_;
    if (tid < 64)
        ghw[(size_t)(b * NSTRIP_ + strip) * 64 + tid] = whist[tid];
}

// ---- select2: window hist -> T -> exact-prefix stream -> rank -> emit -----
// LDS overlay: u_ holds sm[18][512] during the fallback strip loop, then
// cursor[4096] + grp[2048] afterwards (fast path uses only the latter).
__global__ __launch_bounds__(1024) void select2_kernel(
    const float* __restrict__ route, const float* __restrict__ unc_r,
    const float* __restrict__ scale, const float* __restrict__ unc,
    const unsigned long long* __restrict__ hotlist,
    const unsigned int* __restrict__ ghw,
    const int* __restrict__ hcnts,
    unsigned long long* __restrict__ fbbuf,
    const int* __restrict__ ih_p, const int* __restrict__ iw_p,
    float* __restrict__ out)
{
    __shared__ __align__(16) unsigned char u_[(ROWS_ + 2) * W_ * 4]; // 36.9 KB
    __shared__ unsigned int hist[NBUK_];                             // 16 KB
    __shared__ int sh_T, sh_nc, sh_fb, sh_fn;

    float (*sm)[W_] = (float (*)[W_])u_;
    unsigned int* cursor = (unsigned int*)u_;                        // 16 KB
    unsigned long long* grp = (unsigned long long*)(u_ + 16384);     // 16 KB

    const int b = blockIdx.x, tid = threadIdx.x;
    const int lane = tid & 63, wid = tid >> 6;

    // Phase A (fast): sum 32 per-strip window hists (8 KB read).
    if (tid == 0) { sh_fb = 0; sh_T = 1; sh_nc = 0; sh_fn = 0; }
    if (tid < 64) hist[WBASE_ + tid] = 0u;
    __syncthreads();
    {
        const unsigned int* gw = ghw + (size_t)b * NSTRIP_ * 64;
        for (int i = tid; i < NSTRIP_ * 64; i += 1024) {
            unsigned int v = gw[i];
            if (v) atomicAdd(&hist[WBASE_ + (i & 63)], v);
        }
    }
    __syncthreads();

    // Phase B (fast, wave0): T within the window, else flag fallback.
    if (wid == 0) {
        int cnt = (int)hist[WBASE_ + lane];
        int sum = cnt;
        #pragma unroll
        for (int off = 32; off > 0; off >>= 1)
            sum += __shfl_down(sum, off, 64);
        sum = __shfl(sum, 0, 64);
        if (sum < K_) {
            if (lane == 0) sh_fb = 1;
        } else {
            int suf = cnt;                       // inclusive suffix over lanes
            #pragma unroll
            for (int off = 1; off < 64; off <<= 1) {
                int o = __shfl_down(suf, off, 64);
                suf += (lane + off < 64) ? o : 0;
            }
            bool cond = suf >= K_;
            unsigned long long mask = __ballot(cond);
            int ls = 63 - __builtin_clzll(mask);
            if (lane >= ls) cursor[WBASE_ + lane] = (unsigned int)(suf - cnt);
            int ncv = __shfl(suf, ls, 64);
            if (lane == 0) { sh_T = WBASE_ + ls; sh_nc = ncv; }
        }
    }
    __syncthreads();
    const int fb = sh_fb;

    if (fb) {
        // ==== Fallback (never taken on sane data): full per-batch recompute.
        for (int i = tid; i < NBUK_; i += 1024) hist[i] = 0u;
        __syncthreads();

        const float4* rb4 = (const float4*)(route + (size_t)b * HW_);
        const float4* ub4 = (const float4*)(unc_r + (size_t)b * HW_);
        unsigned long long* fbb = fbbuf + (size_t)b * FBCAP_;

        for (int strip = 0; strip < NSTRIP_; ++strip) {
            const int r0 = strip * ROWS_;
            __syncthreads();                    // sm free from previous strip
            for (int slot = tid; slot < 2304; slot += 1024) {
                int row = slot >> 7;
                int gy  = r0 - 1 + row;
                int c4  = slot & 127;
                bool okr = (gy >= 0 && gy < H_);
                int cy  = gy < 0 ? 0 : (gy >= H_ ? H_ - 1 : gy);
                float4 r4 = rb4[cy * 128 + c4];
                float4 u4 = ub4[cy * 128 + c4];
                float4 s;
                s.x = score_ref(r4.x, u4.x);
                s.y = score_ref(r4.y, u4.y);
                s.z = score_ref(r4.z, u4.z);
                s.w = score_ref(r4.w, u4.w);
                if (!okr) { s.x = -INFINITY; s.y = -INFINITY;
                            s.z = -INFINITY; s.w = -INFINITY; }
                *(float4*)&sm[row][c4 * 4] = s;
            }
            __syncthreads();
            // Peak test over the 16x512 interior (4-px groups).
            for (int g = tid; g < 2048; g += 1024) {
                int ly = 1 + (g >> 7);           // 1..16
                int x0 = (g & 127) * 4;
                int gy = r0 + (ly - 1);
                float4 q0 = *(const float4*)&sm[ly - 1][x0];
                float4 q1 = *(const float4*)&sm[ly    ][x0];
                float4 q2 = *(const float4*)&sm[ly + 1][x0];
                bool hasL = (x0 > 0), hasR = (x0 + 4 < W_);
                float l0 = hasL ? sm[ly - 1][x0 - 1] : -INFINITY;
                float l1 = hasL ? sm[ly    ][x0 - 1] : -INFINITY;
                float l2 = hasL ? sm[ly + 1][x0 - 1] : -INFINITY;
                float e0 = hasR ? sm[ly - 1][x0 + 4] : -INFINITY;
                float e1 = hasR ? sm[ly    ][x0 + 4] : -INFINITY;
                float e2 = hasR ? sm[ly + 1][x0 + 4] : -INFINITY;
                float f_m1 = fmaxf(l0, fmaxf(l1, l2));
                float f_0  = fmaxf(q0.x, fmaxf(q1.x, q2.x));
                float f_1  = fmaxf(q0.y, fmaxf(q1.y, q2.y));
                float f_2  = fmaxf(q0.z, fmaxf(q1.z, q2.z));
                float f_3  = fmaxf(q0.w, fmaxf(q1.w, q2.w));
                float f_4  = fmaxf(e0, fmaxf(e1, e2));
                float tb0  = fmaxf(q0.x, q2.x);
                float tb1  = fmaxf(q0.y, q2.y);
                float tb2  = fmaxf(q0.z, q2.z);
                float tb3  = fmaxf(q0.w, q2.w);
                float vv[4] = { q1.x, q1.y, q1.z, q1.w };
                float mm[4];
                mm[0] = fmaxf(fmaxf(f_m1, f_1), tb0);
                mm[1] = fmaxf(fmaxf(f_0,  f_2), tb1);
                mm[2] = fmaxf(fmaxf(f_1,  f_3), tb2);
                mm[3] = fmaxf(fmaxf(f_2,  f_4), tb3);
                #pragma unroll
                for (int i = 0; i < 4; ++i) {
                    if (vv[i] >= mm[i]) {
                        unsigned int bits = __float_as_uint(vv[i]);
                        unsigned int idx  = (unsigned int)(gy * W_ + x0 + i);
                        int p = atomicAdd(&sh_fn, 1);
                        if (p < FBCAP_) {
                            fbb[p] = ((unsigned long long)bits << 32)
                                     | (0xFFFFFFFFu - idx);
                            atomicAdd(&hist[bits >> 18], 1u);
                        }
                    }
                }
            }
        }
        __syncthreads();                        // sm dead; hist complete

        // Full T-scan + cursor suffix-init (wave0).
        if (wid == 0) {
            int Tv = 0;
            int total = 0;
            for (int c = NBUK_ / 64 - 1; c >= 0; --c) {
                int cnt = (int)hist[c * 64 + lane];
                int sum = cnt;
                #pragma unroll
                for (int off = 32; off > 0; off >>= 1)
                    sum += __shfl_down(sum, off, 64);
                sum = __shfl(sum, 0, 64);
                if (total + sum < K_) { total += sum; continue; }
                int suf = cnt;
                #pragma unroll
                for (int off = 1; off < 64; off <<= 1) {
                    int o = __shfl_down(suf, off, 64);
                    suf += (lane + off < 64) ? o : 0;
                }
                bool cond = (total + suf) >= K_;
                unsigned long long mask = __ballot(cond);
                int ls = 63 - __builtin_clzll(mask);
                Tv = c * 64 + ls;
                break;
            }
            if (Tv < 1) Tv = 1;
            int run = 0;
            for (int cb = NBUK_ - 64; cb >= (Tv & ~63); cb -= 64) {
                int beta = cb + lane;
                int cnt = (beta >= Tv) ? (int)hist[beta] : 0;
                int suf = cnt;
                #pragma unroll
                for (int off = 1; off < 64; off <<= 1) {
                    int o = __shfl_down(suf, off, 64);
                    suf += (lane + off < 64) ? o : 0;
                }
                int chunk_total = __shfl(suf, 0, 64);
                if (beta >= Tv) cursor[beta] = (unsigned int)(run + (suf - cnt));
                run += chunk_total;
            }
            if (lane == 0) { sh_T = Tv; sh_nc = run; }
        }
    }
    __syncthreads();
    const unsigned int T = (unsigned int)sh_T;

    // Phase C: stream candidates and scatter bucket-grouped into grp.
    if (!fb) {
        // Exact per-strip prefixes: wave w handles strips w, w+16.
        for (int s = wid; s < NSTRIP_; s += 16) {
            int c = hcnts[b * NSTRIP_ + s];
            const unsigned long long* hs =
                hotlist + (size_t)(b * NSTRIP_ + s) * HOTCAP_;
            for (int base = 0; base < c; base += 64) {
                int i = base + lane;
                unsigned long long key = (i < c) ? hs[i] : 0ull;
                unsigned int bk = (unsigned int)(key >> 50);
                if (bk >= T) {
                    unsigned int pos = atomicAdd(&cursor[bk], 1u);
                    if (pos < GCAP_) grp[pos] = key;
                }
            }
        }
    } else {
        const unsigned long long* fbb = fbbuf + (size_t)b * FBCAP_;
        int n = sh_fn; if (n > FBCAP_) n = FBCAP_;
        for (int i = tid; i < n; i += 1024) {
            unsigned long long k = fbb[i];
            unsigned int b0 = (unsigned int)(k >> 50);
            if (b0 >= T) {
                unsigned int pos = atomicAdd(&cursor[b0], 1u);
                if (pos < GCAP_) grp[pos] = k;
            }
        }
    }
    __syncthreads();

    // Phase D: exact descending rank per candidate + direct emit.
    // rank = (#elements in higher buckets) + (#same-bucket keys > mine).
    // Keys unique (idx in low bits) -> identical order to a full desc sort.
    const float fih = (float)(*ih_p);
    const float fiw = (float)(*iw_p);
    float* rois   = out;                       // [B,K,5]
    float* scores = out + (size_t)B_ * K_ * 5; // [B,K]
    float* validf = out + (size_t)B_ * K_ * 6; // [B,K]

    int nc = sh_nc;
    int ncEff = nc < GCAP_ ? nc : GCAP_;
    for (int p = tid; p < ncEff; p += 1024) {
        unsigned long long key = grp[p];
        unsigned int beta = (unsigned int)(key >> 50);
        int segEnd   = (int)cursor[beta];         // start + cnt
        int segStart = segEnd - (int)hist[beta];
        int qEnd = segEnd < GCAP_ ? segEnd : GCAP_;
        int r = 0;
        for (int q = segStart; q < qEnd; ++q)
            r += (grp[q] > key) ? 1 : 0;
        int rank = segStart + r;
        if (rank < K_) {
            int o = b * K_ + rank;
            unsigned int bits = (unsigned int)(key >> 32);
            float v = __uint_as_float(bits);
            unsigned int idx = 0xFFFFFFFFu - (unsigned int)(key & 0xFFFFFFFFull);
            int y = (int)(idx >> 9), x = (int)(idx & 511u);
            float cx = ((float)x + 0.5f) * 4.0f;
            float cy = ((float)y + 0.5f) * 4.0f;
            float ss = sigmoid_fast(scale[(size_t)b * HW_ + idx]);
            float su = sigmoid_fast(unc  [(size_t)b * HW_ + idx]);
            float side = (32.0f + ss * 480.0f) * (1.0f + 0.25f * su);
            float half = 0.5f * side;
            float x1 = fminf(fmaxf(cx - half, 0.0f), fiw - 1.0f);
            float y1 = fminf(fmaxf(cy - half, 0.0f), fih - 1.0f);
            float x2 = fminf(fmaxf(cx + half, 1.0f), fiw);
            float y2 = fminf(fmaxf(cy + half, 1.0f), fih);
            rois[o * 5 + 0] = (float)b;
            rois[o * 5 + 1] = x1; rois[o * 5 + 2] = y1;
            rois[o * 5 + 3] = x2; rois[o * 5 + 4] = y2;
            scores[o] = v; validf[o] = 1.0f;
        }
    }
    // Tail fill (only if fewer than K candidates exist — normally empty).
    for (int k = nc + tid; k < K_; k += 1024) {
        int o = b * K_ + k;
        rois[o * 5 + 0] = 0.0f; rois[o * 5 + 1] = 0.0f;
        rois[o * 5 + 2] = 0.0f; rois[o * 5 + 3] = 0.0f;
        rois[o * 5 + 4] = 0.0f;
        scores[o] = 0.0f; validf[o] = 0.0f;
    }
}

extern "C" void kernel_launch(void* const* d_in, const int* in_sizes, int n_in,
                              void* d_out, int out_size, void* d_ws, size_t ws_size,
                              hipStream_t stream) {
    const float* route = (const float*)d_in[0];
    const float* scale = (const float*)d_in[1];
    const float* unc   = (const float*)d_in[2];
    const int*   ih    = (const int*)d_in[3];
    const int*   iw    = (const int*)d_in[4];
    float* out = (float*)d_out;

    // ws layout (all fast-path regions fully rewritten each launch):
    //   hotlist  7,340,032 B (32 x 32 x 896 x u64)  — fast-path stream
    //   ghw        262,144 B (32 x 32 x 64 x u32)   — window hists
    //   hcnts        4,096 B (32 x 32 x i32)        — exact hot counts
    //   fbbuf   11,534,336 B (32 x 45056 x u64)     — fallback only
    unsigned char* base = (unsigned char*)d_ws;
    unsigned long long* hotlist = (unsigned long long*)base;
    unsigned int* ghw = (unsigned int*)(base + HL_BYTES_);
    int* hcnts        = (int*)(base + HL_BYTES_ + GW_BYTES_);
    unsigned long long* fbbuf =
        (unsigned long long*)(base + HL_BYTES_ + GW_BYTES_ + HC_BYTES_);

    dim3 g(NSTRIP_, B_);      // 32 strips x 32 batches
    fused_peak_kernel<<<g, THR_, 0, stream>>>(route, unc, hotlist, ghw,
                                              hcnts);
    select2_kernel<<<B_, 1024, 0, stream>>>(route, unc, scale, unc,
                                            hotlist, ghw, hcnts, fbbuf,
                                            ih, iw, out);
}